// Round 12
// baseline (111.040 us; speedup 1.0000x reference)
//
#include <hip/hip_runtime.h>
#include <hip/hip_bf16.h>

#define NN 8192
#define BB 4096
#define DD 256
#define TILE 256
#define NT 32                        // NN / TILE
#define NBLK 528                     // NT*(NT+1)/2 triangular tiles (= 8*66, XCD-chunked)
#define BK 32                        // K-step
#define KSCALE 2.8853900817779268f   // 2 * log2(e): exp(sim) = exp2(KSCALE * dot)

typedef __attribute__((ext_vector_type(8))) short short8;
typedef __attribute__((ext_vector_type(4))) float f32x4;

static __device__ __forceinline__ float exp2_fast(float x) {
    float r; asm("v_exp_f32 %0, %1" : "=v"(r) : "v"(x)); return r;
}
static __device__ __forceinline__ ushort f2bf(float x) {
    __hip_bfloat16 h = __float2bfloat16(x);
    return *reinterpret_cast<ushort*>(&h);
}
static __device__ __forceinline__ float bf2f(short u) {
    unsigned int x = (unsigned int)(ushort)u << 16;
    float f; __builtin_memcpy(&f, &x, 4); return f;
}

static __device__ __forceinline__ void tri_decode(int bid, int& bi, int& bj) {
    int idx = (bid & 7) * (NBLK / 8) + (bid >> 3);   // XCD-chunked, bijective
    int b = (int)((sqrtf(8.0f * (float)idx + 1.0f) - 1.0f) * 0.5f);
    while ((b + 1) * (b + 2) / 2 <= idx) ++b;
    while (b * (b + 1) / 2 > idx) --b;
    bj = b;
    bi = idx - b * (b + 1) / 2;
}

// Kernel 1: L2-normalize rows of concat(z_i,z_j) -> zn (bf16) and zns = KSCALE*zn (bf16).
// Block 0 also zeroes the output scalar (no memset dispatch needed).
__global__ __launch_bounds__(256) void norm_kernel(const float* __restrict__ zi,
                                                   const float* __restrict__ zj,
                                                   ushort* __restrict__ zn,
                                                   ushort* __restrict__ zns,
                                                   float* __restrict__ out) {
    if (blockIdx.x == 0 && threadIdx.x == 0) out[0] = 0.f;
    int row  = (blockIdx.x * 256 + threadIdx.x) >> 6;
    int lane = threadIdx.x & 63;
    const float* src = (row < BB) ? (zi + (size_t)row * DD)
                                  : (zj + (size_t)(row - BB) * DD);
    float4 v = ((const float4*)src)[lane];
    float ss = v.x * v.x + v.y * v.y + v.z * v.z + v.w * v.w;
    #pragma unroll
    for (int m = 32; m; m >>= 1) ss += __shfl_xor(ss, m, 64);
    float inv = 1.0f / fmaxf(sqrtf(ss), 1e-8f);
    ushort4 o, os;
    o.x  = f2bf(v.x * inv);            o.y  = f2bf(v.y * inv);
    o.z  = f2bf(v.z * inv);            o.w  = f2bf(v.w * inv);
    float invs = inv * KSCALE;
    os.x = f2bf(v.x * invs);           os.y = f2bf(v.y * invs);
    os.z = f2bf(v.z * invs);           os.w = f2bf(v.w * invs);
    ((ushort4*)(zn  + (size_t)row * DD))[lane] = o;
    ((ushort4*)(zns + (size_t)row * DD))[lane] = os;
}

// Kernel 2: triangular 256x256 tile (bi<=bj), 512 thr = 8 waves in 2x4 grid.
// Per wave: 128 rows x 64 cols (acc[8][4], static indices only).
// A(zns)+B(zn) staged per BK=32 step into double-buffered LDS via global_load_lds.
// RACE-FREE 2-phase (guide §5.5 T3 minimum recipe): STAGE(k+1) is issued AFTER
// the top-of-iter barrier, so writes to buf (k+1)&1 are program-ordered after
// all iter-(k-1) reads of that buffer. vmcnt(0) at the top waits only stage-k
// (nothing else outstanding) == counted wait; stage-(k+1) latency overlaps the
// whole iter-k MFMA phase. __launch_bounds__(512,2) (min-only): no waves_per_eu
// max-clamp (R9's occupancy bug) -> 2 blocks/CU possible.
// Row/col exp-sums -> disjoint psum[32][NN] writes, NO atomics.
__global__ __launch_bounds__(512, 2)
void sim_kernel(const ushort* __restrict__ zn,
                const ushort* __restrict__ zns,
                float* __restrict__ psum) {
    __shared__ int4  lds4[2][2048];       // [buf][A:0..1023 | B:1024..2047] = 64 KB
    __shared__ float rsum[2][4][128];     // (wr, wc, rowlocal) 4 KB
    __shared__ float csum[4][2][64];      // (wc, wr, collocal) 2 KB

    const int tid  = threadIdx.x;
    const int w    = tid >> 6;
    const int lane = tid & 63;
    const int l15  = lane & 15;
    const int lhi  = lane >> 4;
    const int wr   = w >> 2;              // 0..1: owns rows wr*128..+128
    const int wc   = w & 3;               // 0..3: owns cols wc*64..+64

    int bi, bj; tri_decode(blockIdx.x, bi, bj);
    const int  rowt0   = bi * TILE;
    const int  colt0   = bj * TILE;
    const bool offdiag = (bi != bj);

    // stage K-slice k: 512 panel-rows (A then B) x 32 K. 2048 granules of 16B,
    // 4 per thread. Dest slot d linear; source granule = (d&3) ^ ((r>>2)&3).
    auto STAGE = [&](int buf, int k) {
        #pragma unroll
        for (int i = 0; i < 4; ++i) {
            int d = i * 512 + tid;                   // 0..2047
            int s = d & 1023;                        // slot within panel
            int r = s >> 2, gd = s & 3;
            int gs = gd ^ ((r >> 2) & 3);            // inverse swizzle (XOR involution)
            const ushort* srcp = (i < 2)
                ? zns + (size_t)(rowt0 + r) * DD + k * BK + gs * 8
                : zn  + (size_t)(colt0 + r) * DD + k * BK + gs * 8;
            __builtin_amdgcn_global_load_lds(
                (__attribute__((address_space(1))) void*)srcp,
                (__attribute__((address_space(3))) void*)&lds4[buf][i * 512 + w * 64],
                16, 0, 0);
        }
    };

    f32x4 acc[8][4];
    #pragma unroll
    for (int mi = 0; mi < 8; ++mi)
        #pragma unroll
        for (int ni = 0; ni < 4; ++ni) acc[mi][ni] = (f32x4){0.f, 0.f, 0.f, 0.f};

    STAGE(0, 0);
    __builtin_amdgcn_sched_barrier(0);

    #pragma unroll
    for (int k = 0; k < 8; ++k) {
        // only stage-k loads are outstanding here (k+1 not yet issued)
        asm volatile("s_waitcnt vmcnt(0)" ::: "memory");
        __builtin_amdgcn_s_barrier();        // all waves: buf[k&1] fully in LDS
        __builtin_amdgcn_sched_barrier(0);
        if (k < 7) STAGE((k + 1) & 1, k + 1);   // issued after barrier: WAR-safe vs
                                                // iter-(k-1) readers of this buffer
        __builtin_amdgcn_sched_barrier(0);

        const short8* bufA = (const short8*)&lds4[k & 1][0];
        const short8* bufB = (const short8*)&lds4[k & 1][1024];
        short8 af[8], bf[4];
        #pragma unroll
        for (int mi = 0; mi < 8; ++mi) {
            int r = wr * 128 + mi * 16 + l15;
            af[mi] = bufA[r * 4 + (lhi ^ ((r >> 2) & 3))];
        }
        #pragma unroll
        for (int ni = 0; ni < 4; ++ni) {
            int r = wc * 64 + ni * 16 + l15;
            bf[ni] = bufB[r * 4 + (lhi ^ ((r >> 2) & 3))];
        }
        #pragma unroll
        for (int mi = 0; mi < 8; ++mi)
            #pragma unroll
            for (int ni = 0; ni < 4; ++ni)
                acc[mi][ni] = __builtin_amdgcn_mfma_f32_16x16x32_bf16(af[mi], bf[ni], acc[mi][ni], 0, 0, 0);
    }

    // ---- epilogue: e = exp2(acc); row and col exp-sums ----
    float rpart[8][4];
    float cpart[4];
    #pragma unroll
    for (int mi = 0; mi < 8; ++mi)
        #pragma unroll
        for (int g = 0; g < 4; ++g) rpart[mi][g] = 0.f;
    #pragma unroll
    for (int ni = 0; ni < 4; ++ni) cpart[ni] = 0.f;

    #pragma unroll
    for (int mi = 0; mi < 8; ++mi)
        #pragma unroll
        for (int ni = 0; ni < 4; ++ni)
            #pragma unroll
            for (int g = 0; g < 4; ++g) {
                float e = exp2_fast(acc[mi][ni][g]);
                rpart[mi][g] += e;
                cpart[ni]    += e;
            }

    // rows: reduce across the 16 col-lanes (l15); C/D row = mi*16 + lhi*4 + g
    #pragma unroll
    for (int mi = 0; mi < 8; ++mi)
        #pragma unroll
        for (int g = 0; g < 4; ++g) {
            float v = rpart[mi][g];
            v += __shfl_xor(v, 1, 64); v += __shfl_xor(v, 2, 64);
            v += __shfl_xor(v, 4, 64); v += __shfl_xor(v, 8, 64);
            if (l15 == 0) rsum[wr][wc][mi * 16 + lhi * 4 + g] = v;
        }
    // cols: reduce across the 4 row-groups (lhi); C/D col = ni*16 + l15
    #pragma unroll
    for (int ni = 0; ni < 4; ++ni) {
        float v = cpart[ni];
        v += __shfl_xor(v, 16, 64); v += __shfl_xor(v, 32, 64);
        if (lhi == 0) csum[wc][wr][ni * 16 + l15] = v;
    }
    __syncthreads();

    // disjoint-write: rows -> slot bj; cols -> slot bi (offdiag only)
    if (tid < TILE) {
        int wrT = tid >> 7, rloc = tid & 127;
        psum[(size_t)bj * NN + rowt0 + tid] =
            rsum[wrT][0][rloc] + rsum[wrT][1][rloc] + rsum[wrT][2][rloc] + rsum[wrT][3][rloc];
        if (offdiag) {
            int wcT = tid >> 6, cloc = tid & 63;
            psum[(size_t)bi * NN + colt0 + tid] = csum[wcT][0][cloc] + csum[wcT][1][cloc];
        }
    }
}

// Kernel 3: per row r: val = ln(Sum_s psum[s][r] - exp(s_rr)) - pos_r.
// 16 lanes/row, 64 rows/block (1024 thr), one atomicAdd per block (128 total).
__global__ __launch_bounds__(1024) void reduce_kernel(const ushort* __restrict__ zn,
                                                      const ushort* __restrict__ zns,
                                                      const float* __restrict__ psum,
                                                      float* __restrict__ out) {
    const int tid  = threadIdx.x;
    const int rloc = tid >> 4;                 // 0..63
    const int r    = blockIdx.x * 64 + rloc;
    const int l    = tid & 15;

    float S = psum[(size_t)l * NN + r] + psum[(size_t)(16 + l) * NN + r];

    const ushort* zr = zn  + (size_t)r * DD + l * 16;
    const ushort* sr = zns + (size_t)r * DD + l * 16;
    const ushort* pr = zn  + (size_t)(r ^ BB) * DD + l * 16;
    short8 z0 = *(const short8*)zr, z1 = *(const short8*)(zr + 8);
    short8 s0 = *(const short8*)sr, s1 = *(const short8*)(sr + 8);
    short8 p0 = *(const short8*)pr, p1 = *(const short8*)(pr + 8);
    float ds = 0.f, dp = 0.f;
    #pragma unroll
    for (int k = 0; k < 8; ++k) {
        float za = bf2f(z0[k]), zb = bf2f(z1[k]);
        ds += bf2f(s0[k]) * za + bf2f(s1[k]) * zb;   // KSCALE * self-dot
        dp += bf2f(p0[k]) * za + bf2f(p1[k]) * zb;   // dot with positive pair
    }
    #pragma unroll
    for (int m = 1; m < 16; m <<= 1) {
        S  += __shfl_xor(S,  m, 64);
        ds += __shfl_xor(ds, m, 64);
        dp += __shfl_xor(dp, m, 64);
    }
    __shared__ float red[64];
    if (l == 0) red[rloc] = logf(S - exp2_fast(ds)) - 2.0f * dp;
    __syncthreads();
    if (tid < 64) {
        float v = red[tid];
        #pragma unroll
        for (int m = 32; m; m >>= 1) v += __shfl_xor(v, m, 64);
        if (tid == 0) atomicAdd(out, v * (1.0f / NN));
    }
}

extern "C" void kernel_launch(void* const* d_in, const int* in_sizes, int n_in,
                              void* d_out, int out_size, void* d_ws, size_t ws_size,
                              hipStream_t stream) {
    const float* zi = (const float*)d_in[0];
    const float* zj = (const float*)d_in[1];
    float* out = (float*)d_out;

    char* ws = (char*)d_ws;
    ushort* zn   = (ushort*)ws;                          // 4 MB
    ushort* zns  = (ushort*)(ws + (size_t)NN * DD * 2);  // 4 MB
    float*  psum = (float*)(ws + (size_t)NN * DD * 4);   // 32*8192*4 = 1 MB

    norm_kernel<<<NN / 4, 256, 0, stream>>>(zi, zj, zn, zns, out);
    sim_kernel<<<NBLK, 512, 0, stream>>>(zn, zns, psum);
    reduce_kernel<<<NN / 64, 1024, 0, stream>>>(zn, zns, psum, out);
}